// Round 2
// baseline (219.696 us; speedup 1.0000x reference)
//
#include <hip/hip_runtime.h>
#include <hip/hip_bf16.h>

// SNNDecode: z = x @ W^T  (einsum 'bsh,oh->sbo'), then linear LI scan over seq.
//   v_t = v_{t-1} + a*(i_{t-1} - v_{t-1});  i_t = (1-b)*i_{t-1} + z_t;  out[t]=v_t
//   a = DT*clamp(tau_mem), b = DT*clamp(tau_syn)
// d_out = [voltages (2048*64*128)] ++ [v_f (8192)] ++ [i_f (8192)]  (fp32)
//
// GEMM strategy (round 2): NO LDS, NO barriers. MFMA fragments are loaded
// directly from global with per-lane addresses (A: 32B contiguous fp32 from X,
// converted in-register; B: 16B contiguous bf16 from a pre-converted W copy in
// ws). All k-offsets are compile-time immediates on 8 base pointers, so the
// compiler can pipeline loads arbitrarily deep across the K loop.
// ws layout: [0, 2 MiB) chunk states; [2 MiB, +128 KiB) W in bf16.

typedef __attribute__((ext_vector_type(4))) float f4;
typedef __attribute__((ext_vector_type(8))) short s8;

#define SEQ    2048
#define HID    512
#define CHAINS 8192          // batch(64) * out(128)
#define VOLT   16777216      // SEQ * CHAINS
#define CHUNK  64
#define NCH    32            // SEQ / CHUNK

__device__ __forceinline__ float clamp01(float x) { return fminf(fmaxf(x, 0.f), 1.f); }

// fp32 -> bf16 bits, round-to-nearest-even
__device__ __forceinline__ short f2bf(float f) {
  union { float f; unsigned u; } c; c.f = f;
  unsigned u = c.u;
  unsigned r = (u + 0x7fffu + ((u >> 16) & 1u)) >> 16;
  return (short)r;
}

// ---------------- Phase 0: W (fp32 [128][512]) -> bf16 in ws ---------------
__global__ __launch_bounds__(256) void k_wconv(const float* __restrict__ W,
                                               unsigned short* __restrict__ Wb) {
  const int i = blockIdx.x * 256 + threadIdx.x;   // 8192 threads, 8 elems each
  const f4 lo = ((const f4*)W)[2 * i];
  const f4 hi = ((const f4*)W)[2 * i + 1];
  s8 v;
#pragma unroll
  for (int j = 0; j < 4; ++j) { v[j] = f2bf(lo[j]); v[j + 4] = f2bf(hi[j]); }
  ((s8*)Wb)[i] = v;
}

// ---------------- Phase 1: Z[(t*64+b)*128+o] = sum_h X[b][t][h]*W[o][h] ----
// 128x128 tile, 4 waves (2x2), each wave 64x64 via 4x4 frags of 16x16x32 bf16.
// Fragments loaded directly from global; no LDS, no __syncthreads.
__global__ __launch_bounds__(256, 2) void k_gemm(const float* __restrict__ X,
                                                 const unsigned short* __restrict__ Wb,
                                                 float* __restrict__ Z) {
  const int tid  = threadIdx.x;
  const int m0   = blockIdx.x << 7;   // global row = b*2048 + t
  const int b    = m0 >> 11;          // constant per block (128 | 2048)
  const int t0   = m0 & 2047;
  const int lane = tid & 63;
  const int wid  = tid >> 6;
  const int wmb  = (wid >> 1) << 6;   // wave row base: 0/64
  const int wnb  = (wid & 1) << 6;    // wave col base: 0/64
  const int lr   = lane & 15;
  const int lk   = (lane >> 4) << 3;  // k offset within 32: 0/8/16/24

  // Fragment base pointers (k=0); all k advances are immediate offsets.
  const float* pa[4];
  const unsigned short* pb[4];
#pragma unroll
  for (int mi = 0; mi < 4; ++mi)
    pa[mi] = X + (size_t)(m0 + wmb + (mi << 4) + lr) * HID + lk;
#pragma unroll
  for (int ni = 0; ni < 4; ++ni)
    pb[ni] = Wb + (size_t)(wnb + (ni << 4) + lr) * HID + lk;

  f4 acc[4][4];
#pragma unroll
  for (int mi = 0; mi < 4; ++mi)
#pragma unroll
    for (int ni = 0; ni < 4; ++ni) acc[mi][ni] = (f4){0.f, 0.f, 0.f, 0.f};

#pragma unroll 4
  for (int step = 0; step < 16; ++step) {   // k = step*32
    const int ko = step << 5;
    s8 af[4], bg[4];
#pragma unroll
    for (int mi = 0; mi < 4; ++mi) {
      const f4 lo = *(const f4*)(pa[mi] + ko);
      const f4 hi = *(const f4*)(pa[mi] + ko + 4);
#pragma unroll
      for (int j = 0; j < 4; ++j) { af[mi][j] = f2bf(lo[j]); af[mi][j + 4] = f2bf(hi[j]); }
    }
#pragma unroll
    for (int ni = 0; ni < 4; ++ni)
      bg[ni] = *(const s8*)(pb[ni] + ko);
#pragma unroll
    for (int mi = 0; mi < 4; ++mi)
#pragma unroll
      for (int ni = 0; ni < 4; ++ni)
        acc[mi][ni] = __builtin_amdgcn_mfma_f32_16x16x32_bf16(af[mi], bg[ni],
                                                              acc[mi][ni], 0, 0, 0);
  }

  // Epilogue: C/D layout col=lane&15, row=(lane>>4)*4+reg (m89-verified).
  const int rr = (lane >> 4) << 2;
#pragma unroll
  for (int mi = 0; mi < 4; ++mi) {
    const int trow = t0 + wmb + (mi << 4) + rr;
#pragma unroll
    for (int ni = 0; ni < 4; ++ni) {
      const int col = wnb + (ni << 4) + lr;
#pragma unroll
      for (int r = 0; r < 4; ++r)
        Z[(size_t)(trow + r) * 8192 + (b << 7) + col] = acc[mi][ni][r];
    }
  }
}

// ---------------- Phase 2a: per-chunk scan from zero state, record end states.
__global__ __launch_bounds__(256) void k_states(const float* __restrict__ tau_syn,
                                                const float* __restrict__ tau_mem,
                                                const float* __restrict__ Z,
                                                float* __restrict__ ws) {
  const int tid = threadIdx.x;
  const int cg = (blockIdx.x & 31) * 64 + (tid & 63);  // 0..2047 chain-group of 4
  const int q  = (blockIdx.x >> 5) * 4 + (tid >> 6);   // 0..31 chunk
  const float a  = 0.001f * clamp01(tau_mem[0]);
  const float bb = 0.001f * clamp01(tau_syn[0]);
  const float eb = 1.f - bb;
  const f4* z4 = (const f4*)Z;
  f4 v = (f4){0.f, 0.f, 0.f, 0.f}, ii = (f4){0.f, 0.f, 0.f, 0.f};
  const int tb = q << 6;
#pragma unroll 8
  for (int j = 0; j < CHUNK; ++j) {
    f4 z = z4[(size_t)(tb + j) * 2048 + cg];
    v  = v + a * (ii - v);
    ii = eb * ii + z;
  }
  f4* vend = (f4*)ws;          // [NCH][2048] f4
  f4* iend = vend + NCH * 2048;
  vend[q * 2048 + cg] = v;
  iend[q * 2048 + cg] = ii;
}

// ---------------- Phase 2b: combine chunk states along time; emit finals.
__global__ __launch_bounds__(256) void k_combine(const float* __restrict__ tau_syn,
                                                 const float* __restrict__ tau_mem,
                                                 float* __restrict__ Out,
                                                 float* __restrict__ ws) {
  const int c = blockIdx.x * 256 + threadIdx.x;  // chain 0..8191
  const float a  = 0.001f * clamp01(tau_mem[0]);
  const float bb = 0.001f * clamp01(tau_syn[0]);
  const float ea = 1.f - a, eb = 1.f - bb;
  float P = 1.f, Q = 0.f, R = 1.f;
#pragma unroll
  for (int j = 0; j < CHUNK; ++j) { float Pn = P * ea; Q = P * a + Q * eb; P = Pn; R *= eb; }
  float* vend = ws;
  float* iend = ws + NCH * CHAINS;
  float sv = 0.f, si = 0.f;
  for (int q = 0; q < NCH; ++q) {
    const int idx = q * CHAINS + c;
    const float ve = vend[idx], ie = iend[idx];
    vend[idx] = sv;  iend[idx] = si;   // overwrite with in-states (in-place)
    const float nv = P * sv + Q * si + ve;
    si = R * si + ie;
    sv = nv;
  }
  Out[VOLT + c] = sv;            // v_f
  Out[VOLT + CHAINS + c] = si;   // i_f
}

// ---------------- Phase 2c: exact per-chunk re-scan from true in-state;
// writes v over z in place (each (t,chain) owned by exactly one thread).
__global__ __launch_bounds__(256) void k_emit(const float* __restrict__ tau_syn,
                                              const float* __restrict__ tau_mem,
                                              float* Z,
                                              const float* __restrict__ ws) {
  const int tid = threadIdx.x;
  const int cg = (blockIdx.x & 31) * 64 + (tid & 63);
  const int q  = (blockIdx.x >> 5) * 4 + (tid >> 6);
  const float a  = 0.001f * clamp01(tau_mem[0]);
  const float bb = 0.001f * clamp01(tau_syn[0]);
  const float eb = 1.f - bb;
  f4* z4 = (f4*)Z;
  const f4* vin = (const f4*)ws;
  const f4* iin = vin + NCH * 2048;
  f4 v  = vin[q * 2048 + cg];
  f4 ii = iin[q * 2048 + cg];
  const int tb = q << 6;
#pragma unroll 8
  for (int j = 0; j < CHUNK; ++j) {
    const size_t idx = (size_t)(tb + j) * 2048 + cg;
    f4 z = z4[idx];
    v  = v + a * (ii - v);
    z4[idx] = v;
    ii = eb * ii + z;
  }
}

extern "C" void kernel_launch(void* const* d_in, const int* in_sizes, int n_in,
                              void* d_out, int out_size, void* d_ws, size_t ws_size,
                              hipStream_t stream) {
  const float* X   = (const float*)d_in[0];  // [64][2048][512]
  const float* W   = (const float*)d_in[1];  // [128][512]
  const float* tsy = (const float*)d_in[2];
  const float* tme = (const float*)d_in[3];
  float* Out = (float*)d_out;
  float* ws  = (float*)d_ws;                 // needs 2 MiB + 128 KiB
  unsigned short* Wb = (unsigned short*)((char*)d_ws + (2u << 20));

  k_wconv<<<32, 256, 0, stream>>>(W, Wb);               // W -> bf16
  k_gemm<<<1024, 256, 0, stream>>>(X, Wb, Out);         // z -> voltages region
  k_states<<<256, 256, 0, stream>>>(tsy, tme, Out, ws); // chunk end states
  k_combine<<<32, 256, 0, stream>>>(tsy, tme, Out, ws); // in-states + v_f/i_f
  k_emit<<<256, 256, 0, stream>>>(tsy, tme, Out, ws);   // v over z, in place
}

// Round 3
// 128.102 us; speedup vs baseline: 1.7150x; 1.7150x over previous
//
#include <hip/hip_runtime.h>
#include <hip/hip_bf16.h>

// SNNDecode: z = x @ W^T  (einsum 'bsh,oh->sbo'), then linear LI scan over seq.
//   v_t = v_{t-1} + a*(i_{t-1} - v_{t-1});  i_t = (1-b)*i_{t-1} + z_t;  out[t]=v_t
//   a = DT*clamp(tau_mem), b = DT*clamp(tau_syn)
// d_out = [voltages (2048*64*128)] ++ [v_f (8192)] ++ [i_f (8192)]  (fp32)
//
// GEMM (round 3): LDS-staged 128x128 tile, BK=64, DOUBLE-BUFFERED with one
// barrier per K-step and register prefetch one step ahead. B comes from a
// pre-converted bf16 W copy (no cvt in the hot loop); A is cvt'd fp32->bf16
// during staging. XOR-swizzled LDS (round-1-verified, conflict-free).
// ws layout: [0, 2 MiB) chunk states; [2 MiB, +128 KiB) W in bf16.

typedef __attribute__((ext_vector_type(4))) float f4;
typedef __attribute__((ext_vector_type(8))) short s8;

#define SEQ    2048
#define HID    512
#define CHAINS 8192          // batch(64) * out(128)
#define VOLT   16777216      // SEQ * CHAINS
#define CHUNK  64
#define NCH    32            // SEQ / CHUNK

__device__ __forceinline__ float clamp01(float x) { return fminf(fmaxf(x, 0.f), 1.f); }

// fp32 -> bf16 bits, round-to-nearest-even
__device__ __forceinline__ short f2bf(float f) {
  union { float f; unsigned u; } c; c.f = f;
  unsigned u = c.u;
  unsigned r = (u + 0x7fffu + ((u >> 16) & 1u)) >> 16;
  return (short)r;
}

// LDS swizzle (ushort-index units): XOR row-low-bits into k bits 3..5 so both
// ds_write_b128 staging and ds_read_b128 fragment reads hit all 32 banks evenly.
__device__ __forceinline__ int swz(int row, int k) {
  return (row * 64 + k) ^ ((row & 7) << 3);
}

// ---------------- Phase 0: W (fp32 [128][512]) -> bf16 in ws ---------------
__global__ __launch_bounds__(256) void k_wconv(const float* __restrict__ W,
                                               unsigned short* __restrict__ Wb) {
  const int i = blockIdx.x * 256 + threadIdx.x;   // 8192 threads, 8 elems each
  const f4 lo = ((const f4*)W)[2 * i];
  const f4 hi = ((const f4*)W)[2 * i + 1];
  s8 v;
#pragma unroll
  for (int j = 0; j < 4; ++j) { v[j] = f2bf(lo[j]); v[j + 4] = f2bf(hi[j]); }
  ((s8*)Wb)[i] = v;
}

// ---------------- Phase 1: Z[(t*64+b)*128+o] = sum_h X[b][t][h]*W[o][h] ----
__global__ __launch_bounds__(256, 2) void k_gemm(const float* __restrict__ X,
                                                 const unsigned short* __restrict__ Wb,
                                                 float* __restrict__ Z) {
  __shared__ short As[2][128 * 64];
  __shared__ short Bs[2][128 * 64];
  const int tid = threadIdx.x;
  const int m0  = blockIdx.x << 7;   // global row = b*2048 + t
  const int b   = m0 >> 11;
  const int t0  = m0 & 2047;

  const int rbase = tid >> 3;        // 0..31: staging row group
  const int coff  = (tid & 7) << 3;  // 0..56: staging k offset (8 elems)

  const int lane = tid & 63;
  const int wid  = tid >> 6;
  const int wmb  = (wid >> 1) << 6;  // wave row base: 0/64
  const int wnb  = (wid & 1) << 6;   // wave col base: 0/64
  const int lr   = lane & 15;
  const int lk   = (lane >> 4) << 3;

  // Staging base pointers (k = coff within tile 0)
  const float* pX[4];
  const unsigned short* pW[4];
#pragma unroll
  for (int c = 0; c < 4; ++c) {
    const int row = (c << 5) + rbase;
    pX[c] = X + (size_t)(m0 + row) * HID + coff;
    pW[c] = Wb + (size_t)row * HID + coff;
  }

  f4 acc[4][4];
#pragma unroll
  for (int mi = 0; mi < 4; ++mi)
#pragma unroll
    for (int ni = 0; ni < 4; ++ni) acc[mi][ni] = (f4){0.f, 0.f, 0.f, 0.f};

  // Register prefetch buffers (ping-pong; indices static after full unroll)
  f4 xa[2][4][2];
  s8 wv[2][4];
#pragma unroll
  for (int c = 0; c < 4; ++c) {
    xa[0][c][0] = *(const f4*)(pX[c]);
    xa[0][c][1] = *(const f4*)(pX[c] + 4);
    wv[0][c]    = *(const s8*)(pW[c]);
  }

#pragma unroll
  for (int ks = 0; ks < 8; ++ks) {
    const int cur = ks & 1;
    // Stage current tile into LDS[cur]
#pragma unroll
    for (int c = 0; c < 4; ++c) {
      const int row = (c << 5) + rbase;
      s8 va;
#pragma unroll
      for (int j = 0; j < 4; ++j) {
        va[j]     = f2bf(xa[cur][c][0][j]);
        va[j + 4] = f2bf(xa[cur][c][1][j]);
      }
      *(s8*)&As[cur][swz(row, coff)] = va;
      *(s8*)&Bs[cur][swz(row, coff)] = wv[cur][c];
    }
    // Issue next tile's global loads (land during MFMA + barrier wait)
    if (ks < 7) {
      const int k0 = (ks + 1) << 6;
#pragma unroll
      for (int c = 0; c < 4; ++c) {
        xa[cur ^ 1][c][0] = *(const f4*)(pX[c] + k0);
        xa[cur ^ 1][c][1] = *(const f4*)(pX[c] + k0 + 4);
        wv[cur ^ 1][c]    = *(const s8*)(pW[c] + k0);
      }
    }
    __syncthreads();   // LDS[cur] writes visible; single barrier per step
    // (safe: reads of LDS[cur^1] from step ks-1 were consumed by that step's
    //  MFMAs before this barrier; next write to LDS[cur^1] is after it)
#pragma unroll
    for (int kk = 0; kk < 2; ++kk) {
      s8 af[4], bg[4];
#pragma unroll
      for (int mi = 0; mi < 4; ++mi)
        af[mi] = *(const s8*)&As[cur][swz(wmb + (mi << 4) + lr, (kk << 5) + lk)];
#pragma unroll
      for (int ni = 0; ni < 4; ++ni)
        bg[ni] = *(const s8*)&Bs[cur][swz(wnb + (ni << 4) + lr, (kk << 5) + lk)];
#pragma unroll
      for (int mi = 0; mi < 4; ++mi)
#pragma unroll
        for (int ni = 0; ni < 4; ++ni)
          acc[mi][ni] = __builtin_amdgcn_mfma_f32_16x16x32_bf16(af[mi], bg[ni],
                                                                acc[mi][ni], 0, 0, 0);
    }
  }

  // Epilogue: C/D layout col=lane&15, row=(lane>>4)*4+reg (m89-verified).
  const int rr = (lane >> 4) << 2;
#pragma unroll
  for (int mi = 0; mi < 4; ++mi) {
    const int trow = t0 + wmb + (mi << 4) + rr;
#pragma unroll
    for (int ni = 0; ni < 4; ++ni) {
      const int col = wnb + (ni << 4) + lr;
#pragma unroll
      for (int r = 0; r < 4; ++r)
        Z[(size_t)(trow + r) * 8192 + (b << 7) + col] = acc[mi][ni][r];
    }
  }
}

// ---------------- Phase 2a: per-chunk scan from zero state, record end states.
__global__ __launch_bounds__(256) void k_states(const float* __restrict__ tau_syn,
                                                const float* __restrict__ tau_mem,
                                                const float* __restrict__ Z,
                                                float* __restrict__ ws) {
  const int tid = threadIdx.x;
  const int cg = (blockIdx.x & 31) * 64 + (tid & 63);  // 0..2047 chain-group of 4
  const int q  = (blockIdx.x >> 5) * 4 + (tid >> 6);   // 0..31 chunk
  const float a  = 0.001f * clamp01(tau_mem[0]);
  const float bb = 0.001f * clamp01(tau_syn[0]);
  const float eb = 1.f - bb;
  const f4* z4 = (const f4*)Z;
  f4 v = (f4){0.f, 0.f, 0.f, 0.f}, ii = (f4){0.f, 0.f, 0.f, 0.f};
  const int tb = q << 6;
#pragma unroll 8
  for (int j = 0; j < CHUNK; ++j) {
    f4 z = z4[(size_t)(tb + j) * 2048 + cg];
    v  = v + a * (ii - v);
    ii = eb * ii + z;
  }
  f4* vend = (f4*)ws;          // [NCH][2048] f4
  f4* iend = vend + NCH * 2048;
  vend[q * 2048 + cg] = v;
  iend[q * 2048 + cg] = ii;
}

// ---------------- Phase 2b: combine chunk states along time; emit finals.
__global__ __launch_bounds__(256) void k_combine(const float* __restrict__ tau_syn,
                                                 const float* __restrict__ tau_mem,
                                                 float* __restrict__ Out,
                                                 float* __restrict__ ws) {
  const int c = blockIdx.x * 256 + threadIdx.x;  // chain 0..8191
  const float a  = 0.001f * clamp01(tau_mem[0]);
  const float bb = 0.001f * clamp01(tau_syn[0]);
  const float ea = 1.f - a, eb = 1.f - bb;
  float P = 1.f, Q = 0.f, R = 1.f;
#pragma unroll
  for (int j = 0; j < CHUNK; ++j) { float Pn = P * ea; Q = P * a + Q * eb; P = Pn; R *= eb; }
  float* vend = ws;
  float* iend = ws + NCH * CHAINS;
  float sv = 0.f, si = 0.f;
  for (int q = 0; q < NCH; ++q) {
    const int idx = q * CHAINS + c;
    const float ve = vend[idx], ie = iend[idx];
    vend[idx] = sv;  iend[idx] = si;   // overwrite with in-states (in-place)
    const float nv = P * sv + Q * si + ve;
    si = R * si + ie;
    sv = nv;
  }
  Out[VOLT + c] = sv;            // v_f
  Out[VOLT + CHAINS + c] = si;   // i_f
}

// ---------------- Phase 2c: exact per-chunk re-scan from true in-state;
// writes v over z in place (each (t,chain) owned by exactly one thread).
__global__ __launch_bounds__(256) void k_emit(const float* __restrict__ tau_syn,
                                              const float* __restrict__ tau_mem,
                                              float* Z,
                                              const float* __restrict__ ws) {
  const int tid = threadIdx.x;
  const int cg = (blockIdx.x & 31) * 64 + (tid & 63);
  const int q  = (blockIdx.x >> 5) * 4 + (tid >> 6);
  const float a  = 0.001f * clamp01(tau_mem[0]);
  const float bb = 0.001f * clamp01(tau_syn[0]);
  const float eb = 1.f - bb;
  f4* z4 = (f4*)Z;
  const f4* vin = (const f4*)ws;
  const f4* iin = vin + NCH * 2048;
  f4 v  = vin[q * 2048 + cg];
  f4 ii = iin[q * 2048 + cg];
  const int tb = q << 6;
#pragma unroll 8
  for (int j = 0; j < CHUNK; ++j) {
    const size_t idx = (size_t)(tb + j) * 2048 + cg;
    f4 z = z4[idx];
    v  = v + a * (ii - v);
    z4[idx] = v;
    ii = eb * ii + z;
  }
}

extern "C" void kernel_launch(void* const* d_in, const int* in_sizes, int n_in,
                              void* d_out, int out_size, void* d_ws, size_t ws_size,
                              hipStream_t stream) {
  const float* X   = (const float*)d_in[0];  // [64][2048][512]
  const float* W   = (const float*)d_in[1];  // [128][512]
  const float* tsy = (const float*)d_in[2];
  const float* tme = (const float*)d_in[3];
  float* Out = (float*)d_out;
  float* ws  = (float*)d_ws;                 // needs 2 MiB + 128 KiB
  unsigned short* Wb = (unsigned short*)((char*)d_ws + (2u << 20));

  k_wconv<<<32, 256, 0, stream>>>(W, Wb);               // W -> bf16
  k_gemm<<<1024, 256, 0, stream>>>(X, Wb, Out);         // z -> voltages region
  k_states<<<256, 256, 0, stream>>>(tsy, tme, Out, ws); // chunk end states
  k_combine<<<32, 256, 0, stream>>>(tsy, tme, Out, ws); // in-states + v_f/i_f
  k_emit<<<256, 256, 0, stream>>>(tsy, tme, Out, ws);   // v over z, in place
}

// Round 4
// 113.676 us; speedup vs baseline: 1.9326x; 1.1269x over previous
//
#include <hip/hip_runtime.h>
#include <hip/hip_bf16.h>

// SNNDecode: z = x @ W^T  (einsum 'bsh,oh->sbo'), then linear LI scan over seq.
//   v_t = v_{t-1} + a*(i_{t-1} - v_{t-1});  i_t = (1-b)*i_{t-1} + z_t;  out[t]=v_t
// d_out = [voltages (2048*64*128)] ++ [v_f (8192)] ++ [i_f (8192)]  (fp32)
//
// Round 4: (1) prefetch issued AFTER __syncthreads (barrier drain is free;
// latency hides under ds_read+MFMA), (2) packed bf16 cvt, (3) phase-2a chunk
// scan fused into the gemm epilogue via LDS tile (k_states kernel deleted),
// with 512B-coalesced Z stores from LDS.
// ws layout: [0, 2 MiB) chunk states (vend | iend); [2 MiB, +128 KiB) bf16 W.

typedef __attribute__((ext_vector_type(4))) float    f4;
typedef __attribute__((ext_vector_type(8))) short    s8;
typedef __attribute__((ext_vector_type(4))) unsigned u4;

#define SEQ    2048
#define HID    512
#define CHAINS 8192          // batch(64) * out(128)
#define VOLT   16777216      // SEQ * CHAINS
#define NCH    32            // SEQ / 64

__device__ __forceinline__ float clamp01(float x) { return fminf(fmaxf(x, 0.f), 1.f); }

// packed fp32x2 -> bf16x2 (RNE) as one u32; compiler emits v_cvt_pk_bf16_f32
__device__ __forceinline__ unsigned pkbf(float x, float y) {
  float2 t; t.x = x; t.y = y;
  union { __hip_bfloat162 h; unsigned u; } c;
  c.h = __float22bfloat162_rn(t);
  return c.u;
}

// fp32 -> bf16 bits (RNE), scalar (wconv only)
__device__ __forceinline__ short f2bf(float f) {
  union { float f; unsigned u; } c; c.f = f;
  unsigned u = c.u;
  unsigned r = (u + 0x7fffu + ((u >> 16) & 1u)) >> 16;
  return (short)r;
}

// LDS swizzle (ushort-index units): XOR row-low-bits into k bits 3..5 so both
// ds_write_b128 staging and ds_read_b128 fragment reads hit all banks evenly.
__device__ __forceinline__ int swz(int row, int k) {
  return (row * 64 + k) ^ ((row & 7) << 3);
}

// ---------------- Phase 0: W (fp32 [128][512]) -> bf16 in ws ---------------
__global__ __launch_bounds__(256) void k_wconv(const float* __restrict__ W,
                                               unsigned short* __restrict__ Wb) {
  const int i = blockIdx.x * 256 + threadIdx.x;   // 8192 threads, 8 elems each
  const f4 lo = ((const f4*)W)[2 * i];
  const f4 hi = ((const f4*)W)[2 * i + 1];
  s8 v;
#pragma unroll
  for (int j = 0; j < 4; ++j) { v[j] = f2bf(lo[j]); v[j + 4] = f2bf(hi[j]); }
  ((s8*)Wb)[i] = v;
}

// ---------------- Phase 1 (+2a): GEMM tile + Z store + fused chunk scan ----
__global__ __launch_bounds__(256, 2) void k_gemm(const float* __restrict__ X,
                                                 const unsigned short* __restrict__ Wb,
                                                 float* __restrict__ Z,
                                                 const float* __restrict__ tau_syn,
                                                 const float* __restrict__ tau_mem,
                                                 float* __restrict__ ws) {
  __shared__ __align__(16) char smem[65536];
  short* const AS = (short*)smem;            // [2][8192] bf16 A tiles
  short* const BS = (short*)(smem + 32768);  // [2][8192] bf16 B tiles
  float* const ZS = (float*)smem;            // [128][128] z tile (aliased later)

  const int tid = threadIdx.x;
  const int blk = blockIdx.x;
  const int m0  = blk << 7;          // global row = b*2048 + t
  const int bI  = blk >> 4;          // batch index
  const int t0  = (blk & 15) << 7;   // t tile base

  const int rbase = tid >> 3;        // 0..31: staging row group
  const int coff  = (tid & 7) << 3;  // staging k offset (8 elems)

  const int lane = tid & 63;
  const int wid  = tid >> 6;
  const int wmb  = (wid >> 1) << 6;  // wave row base: 0/64
  const int wnb  = (wid & 1) << 6;   // wave col base: 0/64
  const int lr   = lane & 15;
  const int lk   = (lane >> 4) << 3;

  const float* pX[4];
  const unsigned short* pW[4];
#pragma unroll
  for (int c = 0; c < 4; ++c) {
    const int row = (c << 5) + rbase;
    pX[c] = X + (size_t)(m0 + row) * HID + coff;
    pW[c] = Wb + (size_t)row * HID + coff;
  }

  f4 acc[4][4];
#pragma unroll
  for (int mi = 0; mi < 4; ++mi)
#pragma unroll
    for (int ni = 0; ni < 4; ++ni) acc[mi][ni] = (f4){0.f, 0.f, 0.f, 0.f};

  // Register prefetch (ping-pong, static indices via full unroll)
  f4 xa[2][4][2];
  s8 wv[2][4];
#pragma unroll
  for (int c = 0; c < 4; ++c) {
    xa[0][c][0] = *(const f4*)(pX[c]);
    xa[0][c][1] = *(const f4*)(pX[c] + 4);
    wv[0][c]    = *(const s8*)(pW[c]);
  }

#pragma unroll
  for (int ks = 0; ks < 8; ++ks) {
    const int cur = ks & 1;
    short* const Ac = AS + (cur << 13);
    short* const Bc = BS + (cur << 13);
    // Stage current tile into LDS[cur] (consumes xa/wv[cur]; nothing else in
    // flight, so the barrier's implicit vmcnt(0) drain below is free).
#pragma unroll
    for (int c = 0; c < 4; ++c) {
      const int row = (c << 5) + rbase;
      u4 va;
      va[0] = pkbf(xa[cur][c][0][0], xa[cur][c][0][1]);
      va[1] = pkbf(xa[cur][c][0][2], xa[cur][c][0][3]);
      va[2] = pkbf(xa[cur][c][1][0], xa[cur][c][1][1]);
      va[3] = pkbf(xa[cur][c][1][2], xa[cur][c][1][3]);
      *(u4*)&Ac[swz(row, coff)] = va;
      *(s8*)&Bc[swz(row, coff)] = wv[cur][c];
    }
    __syncthreads();
    // Issue next tile's loads AFTER the barrier: they stay in flight under the
    // ds_read+MFMA phase and are only waited at the next stage.
    if (ks < 7) {
      const int k0 = (ks + 1) << 6;
#pragma unroll
      for (int c = 0; c < 4; ++c) {
        xa[cur ^ 1][c][0] = *(const f4*)(pX[c] + k0);
        xa[cur ^ 1][c][1] = *(const f4*)(pX[c] + k0 + 4);
        wv[cur ^ 1][c]    = *(const s8*)(pW[c] + k0);
      }
    }
#pragma unroll
    for (int kk = 0; kk < 2; ++kk) {
      s8 af[4], bg[4];
#pragma unroll
      for (int mi = 0; mi < 4; ++mi)
        af[mi] = *(const s8*)&Ac[swz(wmb + (mi << 4) + lr, (kk << 5) + lk)];
#pragma unroll
      for (int ni = 0; ni < 4; ++ni)
        bg[ni] = *(const s8*)&Bc[swz(wnb + (ni << 4) + lr, (kk << 5) + lk)];
#pragma unroll
      for (int mi = 0; mi < 4; ++mi)
#pragma unroll
        for (int ni = 0; ni < 4; ++ni)
          acc[mi][ni] = __builtin_amdgcn_mfma_f32_16x16x32_bf16(af[mi], bg[ni],
                                                                acc[mi][ni], 0, 0, 0);
    }
  }

  // ---- Epilogue: park z tile in LDS (aliases dead staging buffers) ----
  __syncthreads();   // all waves done reading AS/BS
  const int rr = (lane >> 4) << 2;
#pragma unroll
  for (int mi = 0; mi < 4; ++mi)
#pragma unroll
    for (int ni = 0; ni < 4; ++ni)
#pragma unroll
      for (int r = 0; r < 4; ++r)
        ZS[(wmb + (mi << 4) + rr + r) * 128 + wnb + (ni << 4) + lr] = acc[mi][ni][r];
  __syncthreads();

  // (a) stream z tile to global: f4, 512B-contiguous per 32-lane half
  {
    float* const Zrow = Z + (size_t)t0 * 8192 + (bI << 7);
#pragma unroll
    for (int i = 0; i < 16; ++i) {
      const int idx  = (i << 8) + tid;
      const int toff = idx >> 5;
      const int c4   = idx & 31;
      *(f4*)(Zrow + (size_t)toff * 8192 + (c4 << 2)) = *(const f4*)&ZS[toff * 128 + (c4 << 2)];
    }
  }
  // (b) fused phase 2a: zero-state scan of the 2 chunks this block owns
  {
    const float a  = 0.001f * clamp01(tau_mem[0]);
    const float eb = 1.f - 0.001f * clamp01(tau_syn[0]);
    const int h = tid >> 7, col = tid & 127;
    const float* zs = ZS + ((h << 6) * 128) + col;
    float v = 0.f, ii = 0.f;
#pragma unroll 8
    for (int j = 0; j < 64; ++j) {
      const float z = zs[j * 128];   // bank = col%32: conflict-free across lanes
      v  = v + a * (ii - v);
      ii = eb * ii + z;
    }
    const int q     = ((blk & 15) << 1) + h;   // chunk index 0..31
    const int chain = (bI << 7) + col;         // b*128 + o
    ws[q * CHAINS + chain]                 = v;   // vend
    ws[NCH * CHAINS + q * CHAINS + chain]  = ii;  // iend
  }
}

// ---------------- Phase 2b: combine chunk states along time; emit finals.
__global__ __launch_bounds__(256) void k_combine(const float* __restrict__ tau_syn,
                                                 const float* __restrict__ tau_mem,
                                                 float* __restrict__ Out,
                                                 float* __restrict__ ws) {
  const int c = blockIdx.x * 256 + threadIdx.x;  // chain 0..8191
  const float a  = 0.001f * clamp01(tau_mem[0]);
  const float bb = 0.001f * clamp01(tau_syn[0]);
  const float ea = 1.f - a, eb = 1.f - bb;
  float P = 1.f, Q = 0.f, R = 1.f;
#pragma unroll
  for (int j = 0; j < 64; ++j) { float Pn = P * ea; Q = P * a + Q * eb; P = Pn; R *= eb; }
  float* vend = ws;
  float* iend = ws + NCH * CHAINS;
  float sv = 0.f, si = 0.f;
  for (int q = 0; q < NCH; ++q) {
    const int idx = q * CHAINS + c;
    const float ve = vend[idx], ie = iend[idx];
    vend[idx] = sv;  iend[idx] = si;   // overwrite with in-states (in-place)
    const float nv = P * sv + Q * si + ve;
    si = R * si + ie;
    sv = nv;
  }
  Out[VOLT + c] = sv;            // v_f
  Out[VOLT + CHAINS + c] = si;   // i_f
}

// ---------------- Phase 2c: exact per-chunk re-scan from true in-state;
// writes v over z in place (each (t,chain) owned by exactly one thread).
__global__ __launch_bounds__(256) void k_emit(const float* __restrict__ tau_syn,
                                              const float* __restrict__ tau_mem,
                                              float* Z,
                                              const float* __restrict__ ws) {
  const int tid = threadIdx.x;
  const int cg = (blockIdx.x & 31) * 64 + (tid & 63);  // chain-group of 4
  const int q  = (blockIdx.x >> 5) * 4 + (tid >> 6);   // chunk
  const float a  = 0.001f * clamp01(tau_mem[0]);
  const float eb = 1.f - 0.001f * clamp01(tau_syn[0]);
  f4* z4 = (f4*)Z;
  const f4* vin = (const f4*)ws;
  const f4* iin = vin + NCH * 2048;
  f4 v  = vin[q * 2048 + cg];
  f4 ii = iin[q * 2048 + cg];
  const int tb = q << 6;
#pragma unroll 8
  for (int j = 0; j < 64; ++j) {
    const size_t idx = (size_t)(tb + j) * 2048 + cg;
    f4 z = z4[idx];
    v  = v + a * (ii - v);
    z4[idx] = v;
    ii = eb * ii + z;
  }
}

extern "C" void kernel_launch(void* const* d_in, const int* in_sizes, int n_in,
                              void* d_out, int out_size, void* d_ws, size_t ws_size,
                              hipStream_t stream) {
  const float* X   = (const float*)d_in[0];  // [64][2048][512]
  const float* W   = (const float*)d_in[1];  // [128][512]
  const float* tsy = (const float*)d_in[2];
  const float* tme = (const float*)d_in[3];
  float* Out = (float*)d_out;
  float* ws  = (float*)d_ws;                 // needs 2 MiB + 128 KiB
  unsigned short* Wb = (unsigned short*)((char*)d_ws + (2u << 20));

  k_wconv<<<32, 256, 0, stream>>>(W, Wb);                         // W -> bf16
  k_gemm<<<1024, 256, 0, stream>>>(X, Wb, Out, tsy, tme, ws);     // z + chunk states
  k_combine<<<32, 256, 0, stream>>>(tsy, tme, Out, ws);           // in-states + finals
  k_emit<<<256, 256, 0, stream>>>(tsy, tme, Out, ws);             // v over z, in place
}

// Round 5
// 104.645 us; speedup vs baseline: 2.0994x; 1.0863x over previous
//
#include <hip/hip_runtime.h>
#include <hip/hip_bf16.h>

// SNNDecode: z = x @ W^T  (einsum 'bsh,oh->sbo'), then linear LI scan over seq.
//   v_t = v_{t-1} + a*(i_{t-1} - v_{t-1});  i_t = (1-b)*i_{t-1} + z_t;  out[t]=v_t
// d_out = [voltages (2048*64*128)] ++ [v_f (8192)] ++ [i_f (8192)]  (fp32)
//
// Round 5: (1) B never staged in LDS -- W (128KB bf16) is L2-resident, B MFMA
// fragments are loaded straight from global (contiguous 16B/lane). (2) A
// prefetch deepened to ring-3 (2 K-steps ahead); bg loads are issued BEFORE
// the xa prefetch each iter so vmcnt in-order drains don't kill the depth.
// (3) k_emit at 2x occupancy (512 blocks, float2 chains).
// ws layout: [0, 2 MiB) chunk states (vend | iend); [2 MiB, +128 KiB) bf16 W.

typedef __attribute__((ext_vector_type(4))) float    f4;
typedef __attribute__((ext_vector_type(2))) float    f2;
typedef __attribute__((ext_vector_type(8))) short    s8;
typedef __attribute__((ext_vector_type(4))) unsigned u4;

#define SEQ    2048
#define HID    512
#define CHAINS 8192          // batch(64) * out(128)
#define VOLT   16777216      // SEQ * CHAINS
#define NCH    32            // SEQ / 64

__device__ __forceinline__ float clamp01(float x) { return fminf(fmaxf(x, 0.f), 1.f); }

// packed fp32x2 -> bf16x2 (RNE) as one u32; compiler emits v_cvt_pk_bf16_f32
__device__ __forceinline__ unsigned pkbf(float x, float y) {
  float2 t; t.x = x; t.y = y;
  union { __hip_bfloat162 h; unsigned u; } c;
  c.h = __float22bfloat162_rn(t);
  return c.u;
}

// fp32 -> bf16 bits (RNE), scalar (wconv only)
__device__ __forceinline__ short f2bf(float f) {
  union { float f; unsigned u; } c; c.f = f;
  unsigned u = c.u;
  unsigned r = (u + 0x7fffu + ((u >> 16) & 1u)) >> 16;
  return (short)r;
}

// LDS swizzle (ushort-index units): XOR row-low-bits into k bits 3..5 so both
// ds_write_b128 staging and ds_read_b128 fragment reads hit all banks evenly.
__device__ __forceinline__ int swz(int row, int k) {
  return (row * 64 + k) ^ ((row & 7) << 3);
}

// ---------------- Phase 0: W (fp32 [128][512]) -> bf16 in ws ---------------
__global__ __launch_bounds__(256) void k_wconv(const float* __restrict__ W,
                                               unsigned short* __restrict__ Wb) {
  const int i = blockIdx.x * 256 + threadIdx.x;   // 8192 threads, 8 elems each
  const f4 lo = ((const f4*)W)[2 * i];
  const f4 hi = ((const f4*)W)[2 * i + 1];
  s8 v;
#pragma unroll
  for (int j = 0; j < 4; ++j) { v[j] = f2bf(lo[j]); v[j + 4] = f2bf(hi[j]); }
  ((s8*)Wb)[i] = v;
}

// ---------------- Phase 1 (+2a): GEMM tile + Z store + fused chunk scan ----
__global__ __launch_bounds__(256, 2) void k_gemm(const float* __restrict__ X,
                                                 const unsigned short* __restrict__ Wb,
                                                 float* __restrict__ Z,
                                                 const float* __restrict__ tau_syn,
                                                 const float* __restrict__ tau_mem,
                                                 float* __restrict__ ws) {
  __shared__ __align__(16) char smem[65536];
  short* const AS = (short*)smem;            // [2][128][64] bf16 A tiles (32 KB)
  float* const ZS = (float*)smem;            // [128][128] f32 z tile (aliased)

  const int tid = threadIdx.x;
  const int blk = blockIdx.x;
  const int m0  = blk << 7;          // global row = b*2048 + t
  const int bI  = blk >> 4;          // batch index
  const int t0  = (blk & 15) << 7;   // t tile base

  const int rbase = tid >> 3;        // 0..31: staging row group
  const int coff  = (tid & 7) << 3;  // staging k offset (8 elems)

  const int lane = tid & 63;
  const int wid  = tid >> 6;
  const int wmb  = (wid >> 1) << 6;  // wave row base: 0/64
  const int wnb  = (wid & 1) << 6;   // wave col base: 0/64
  const int lr   = lane & 15;
  const int lk   = (lane >> 4) << 3;

  const float* pX[4];
#pragma unroll
  for (int c = 0; c < 4; ++c)
    pX[c] = X + (size_t)(m0 + (c << 5) + rbase) * HID + coff;
  const unsigned short* pB[4];
#pragma unroll
  for (int ni = 0; ni < 4; ++ni)
    pB[ni] = Wb + (size_t)(wnb + (ni << 4) + lr) * HID + lk;

  f4 acc[4][4];
#pragma unroll
  for (int mi = 0; mi < 4; ++mi)
#pragma unroll
    for (int ni = 0; ni < 4; ++ni) acc[mi][ni] = (f4){0.f, 0.f, 0.f, 0.f};

  // A register prefetch: ring of 3 (2 steps ahead); static indices via unroll.
  f4 xa[3][4][2];
#pragma unroll
  for (int c = 0; c < 4; ++c) {
    xa[0][c][0] = *(const f4*)(pX[c]);
    xa[0][c][1] = *(const f4*)(pX[c] + 4);
    xa[1][c][0] = *(const f4*)(pX[c] + 64);
    xa[1][c][1] = *(const f4*)(pX[c] + 68);
  }

#pragma unroll
  for (int ks = 0; ks < 8; ++ks) {
    const int cur = ks % 3;
    short* const Ac = AS + ((ks & 1) << 13);
    // Stage current A tile into LDS (consumes xa[cur]; these loads are the
    // oldest outstanding, so this wait leaves deeper prefetch in flight).
#pragma unroll
    for (int c = 0; c < 4; ++c) {
      const int row = (c << 5) + rbase;
      u4 va;
      va[0] = pkbf(xa[cur][c][0][0], xa[cur][c][0][1]);
      va[1] = pkbf(xa[cur][c][0][2], xa[cur][c][0][3]);
      va[2] = pkbf(xa[cur][c][1][0], xa[cur][c][1][1]);
      va[3] = pkbf(xa[cur][c][1][2], xa[cur][c][1][3]);
      *(u4*)&Ac[swz(row, coff)] = va;
    }
    __syncthreads();
    // B fragments for this step, issued BEFORE the deep xa prefetch so their
    // vmcnt-consume (in-order!) does not force the xa loads to drain.
    s8 bg[2][4];
#pragma unroll
    for (int kk = 0; kk < 2; ++kk)
#pragma unroll
      for (int ni = 0; ni < 4; ++ni)
        bg[kk][ni] = *(const s8*)(pB[ni] + (ks << 6) + (kk << 5));
    // Deep prefetch: A tile for step ks+2.
    if (ks < 6) {
      const int k0 = (ks + 2) << 6;
      const int nxt = (ks + 2) % 3;
#pragma unroll
      for (int c = 0; c < 4; ++c) {
        xa[nxt][c][0] = *(const f4*)(pX[c] + k0);
        xa[nxt][c][1] = *(const f4*)(pX[c] + k0 + 4);
      }
    }
#pragma unroll
    for (int kk = 0; kk < 2; ++kk) {
      s8 af[4];
#pragma unroll
      for (int mi = 0; mi < 4; ++mi)
        af[mi] = *(const s8*)&Ac[swz(wmb + (mi << 4) + lr, (kk << 5) + lk)];
#pragma unroll
      for (int mi = 0; mi < 4; ++mi)
#pragma unroll
        for (int ni = 0; ni < 4; ++ni)
          acc[mi][ni] = __builtin_amdgcn_mfma_f32_16x16x32_bf16(af[mi], bg[kk][ni],
                                                                acc[mi][ni], 0, 0, 0);
    }
  }

  // ---- Epilogue: park z tile in LDS (aliases dead staging buffer) ----
  __syncthreads();   // all waves done reading AS
  const int rr = (lane >> 4) << 2;
#pragma unroll
  for (int mi = 0; mi < 4; ++mi)
#pragma unroll
    for (int ni = 0; ni < 4; ++ni)
#pragma unroll
      for (int r = 0; r < 4; ++r)
        ZS[(wmb + (mi << 4) + rr + r) * 128 + wnb + (ni << 4) + lr] = acc[mi][ni][r];
  __syncthreads();

  // (a) stream z tile to global: f4, 512B-contiguous per 32-lane half
  {
    float* const Zrow = Z + (size_t)t0 * 8192 + (bI << 7);
#pragma unroll
    for (int i = 0; i < 16; ++i) {
      const int idx  = (i << 8) + tid;
      const int toff = idx >> 5;
      const int c4   = idx & 31;
      *(f4*)(Zrow + (size_t)toff * 8192 + (c4 << 2)) = *(const f4*)&ZS[toff * 128 + (c4 << 2)];
    }
  }
  // (b) fused phase 2a: zero-state scan of the 2 chunks this block owns
  {
    const float a  = 0.001f * clamp01(tau_mem[0]);
    const float eb = 1.f - 0.001f * clamp01(tau_syn[0]);
    const int h = tid >> 7, col = tid & 127;
    const float* zs = ZS + ((h << 6) * 128) + col;
    float v = 0.f, ii = 0.f;
#pragma unroll 8
    for (int j = 0; j < 64; ++j) {
      const float z = zs[j * 128];   // bank = col%32: conflict-free across lanes
      v  = v + a * (ii - v);
      ii = eb * ii + z;
    }
    const int q     = ((blk & 15) << 1) + h;   // chunk index 0..31
    const int chain = (bI << 7) + col;         // b*128 + o
    ws[q * CHAINS + chain]                 = v;   // vend
    ws[NCH * CHAINS + q * CHAINS + chain]  = ii;  // iend
  }
}

// ---------------- Phase 2b: combine chunk states along time; emit finals.
__global__ __launch_bounds__(256) void k_combine(const float* __restrict__ tau_syn,
                                                 const float* __restrict__ tau_mem,
                                                 float* __restrict__ Out,
                                                 float* __restrict__ ws) {
  const int c = blockIdx.x * 256 + threadIdx.x;  // chain 0..8191
  const float a  = 0.001f * clamp01(tau_mem[0]);
  const float bb = 0.001f * clamp01(tau_syn[0]);
  const float ea = 1.f - a, eb = 1.f - bb;
  float P = 1.f, Q = 0.f, R = 1.f;
#pragma unroll
  for (int j = 0; j < 64; ++j) { float Pn = P * ea; Q = P * a + Q * eb; P = Pn; R *= eb; }
  float* vend = ws;
  float* iend = ws + NCH * CHAINS;
  float sv = 0.f, si = 0.f;
  for (int q = 0; q < NCH; ++q) {
    const int idx = q * CHAINS + c;
    const float ve = vend[idx], ie = iend[idx];
    vend[idx] = sv;  iend[idx] = si;   // overwrite with in-states (in-place)
    const float nv = P * sv + Q * si + ve;
    si = R * si + ie;
    sv = nv;
  }
  Out[VOLT + c] = sv;            // v_f
  Out[VOLT + CHAINS + c] = si;   // i_f
}

// ---------------- Phase 2c: exact per-chunk re-scan from true in-state;
// writes v over z in place. float2 chains -> 512 blocks (2 blocks/CU).
__global__ __launch_bounds__(256) void k_emit(const float* __restrict__ tau_syn,
                                              const float* __restrict__ tau_mem,
                                              float* Z,
                                              const float* __restrict__ ws) {
  const int tid = threadIdx.x;
  const int cg = (blockIdx.x & 63) * 64 + (tid & 63);  // chain pair 0..4095
  const int q  = (blockIdx.x >> 6) * 4 + (tid >> 6);   // chunk 0..31
  const float a  = 0.001f * clamp01(tau_mem[0]);
  const float eb = 1.f - 0.001f * clamp01(tau_syn[0]);
  f2* z2 = (f2*)Z;
  const f2* vin = (const f2*)ws;                 // [NCH][4096] f2
  const f2* iin = vin + NCH * 4096;
  f2 v  = vin[q * 4096 + cg];
  f2 ii = iin[q * 4096 + cg];
  const int tb = q << 6;
#pragma unroll 8
  for (int j = 0; j < 64; ++j) {
    const size_t idx = (size_t)(tb + j) * 4096 + cg;
    f2 z = z2[idx];
    v  = v + a * (ii - v);
    z2[idx] = v;
    ii = eb * ii + z;
  }
}

extern "C" void kernel_launch(void* const* d_in, const int* in_sizes, int n_in,
                              void* d_out, int out_size, void* d_ws, size_t ws_size,
                              hipStream_t stream) {
  const float* X   = (const float*)d_in[0];  // [64][2048][512]
  const float* W   = (const float*)d_in[1];  // [128][512]
  const float* tsy = (const float*)d_in[2];
  const float* tme = (const float*)d_in[3];
  float* Out = (float*)d_out;
  float* ws  = (float*)d_ws;                 // needs 2 MiB + 128 KiB
  unsigned short* Wb = (unsigned short*)((char*)d_ws + (2u << 20));

  k_wconv<<<32, 256, 0, stream>>>(W, Wb);                         // W -> bf16
  k_gemm<<<1024, 256, 0, stream>>>(X, Wb, Out, tsy, tme, ws);     // z + chunk states
  k_combine<<<32, 256, 0, stream>>>(tsy, tme, Out, ws);           // in-states + finals
  k_emit<<<512, 256, 0, stream>>>(tsy, tme, Out, ws);             // v over z, in place
}